// Round 10
// baseline (400.917 us; speedup 1.0000x reference)
//
#include <hip/hip_runtime.h>
#include <hip/hip_bf16.h>

typedef unsigned short u16;
typedef unsigned char u8;
typedef unsigned int u32;
typedef __attribute__((ext_vector_type(8))) short bf16x8;
typedef __attribute__((ext_vector_type(4))) float f32x4;

#define BB 2
#define LL 4096
#define GG 256
#define HH 12
#define DD 64
#define NB 32
#define WW 255
#define VV 32
#define NCHUNK 17
#define LKEY 640      // 384 local-window keys + 256 global keys
#define GKEY 4352     // 256 global keys + 4096 long keys
#define WMAT 589824   // 768*768 elements per weight matrix
#define MMAT 294912   // 384*768 elements per rel-fold matrix

// prep-kernel block ranges
#define PKL_BLK 20480   // BB*LL*LKEY/256
#define PKG_BLK 8704    // BB*2*68*128*64/256
#define WPR_BLK 1152    // 12*12*8
#define XPL_BLK 3072    // BB*LL*768/2048
#define XPG_BLK 192     // BB*GG*768/2048
#define MPR_BLK 768     // 2 sides * 384 n

// ---------- bf16 helpers ----------
__device__ __forceinline__ float bf2f(u16 u) {
  return __uint_as_float(((unsigned)u) << 16);
}
__device__ __forceinline__ u16 f2bf(float f) {
  unsigned u = __float_as_uint(f);
  u += 0x7FFFu + ((u >> 16) & 1u);
  return (u16)(u >> 16);
}
__device__ __forceinline__ float4 ld4bf(const u16* p) {
  ushort4 q = *reinterpret_cast<const ushort4*>(p);
  return make_float4(bf2f(q.x), bf2f(q.y), bf2f(q.z), bf2f(q.w));
}
__device__ __forceinline__ float ldx1(const void* p, size_t idx, bool f32m) {
  if (f32m) return reinterpret_cast<const float*>(p)[idx];
  return bf2f(reinterpret_cast<const u16*>(p)[idx]);
}
// async global->LDS, 16B per lane; dest is wave-uniform base + lane*16
__device__ __forceinline__ void gload16(const u16* src, u16* ldsdst) {
  __builtin_amdgcn_global_load_lds(
      (const __attribute__((address_space(1))) unsigned int*)src,
      (__attribute__((address_space(3))) unsigned int*)ldsdst, 16, 0, 0);
}

// ---------- dtype detector (bf16 N(0,1) never has exponent >= 134) ----------
__global__ void detect_dtype(const void* __restrict__ x, int* __restrict__ flag) {
  __shared__ int cnt;
  if (threadIdx.x == 0) cnt = 0;
  __syncthreads();
  const u16* p = reinterpret_cast<const u16*>(x);
  int c = 0;
  for (int i = threadIdx.x; i < 4096; i += 256) {
    int e = (p[i] >> 7) & 0xFF;
    if (e >= 134) c++;
  }
  atomicAdd(&cnt, c);
  __syncthreads();
  if (threadIdx.x == 0) *flag = (cnt >= 64) ? 1 : 0;
}

// =========================================================================
// prep: pack_l U pack_g U wprep(8 mats) U xprep U M-prep, one launch.
// M-prep: Mt[n=h*32+r][k] = 0.125 * sum_d Wq[k][h*64+d]*emb[r][h][d]
//         c[n] = 0.125 * (sum_d bq[h*64+d]*emb[r][h][d] + rel_bias[r][h])
// so rel_all = x . Mt^T + c  (folds relk into the QKV GEMM).
// =========================================================================
__global__ __launch_bounds__(256)
void prep(const int* __restrict__ m_l2l, const int* __restrict__ m_l2g,
          const int* __restrict__ i_l2l, const int* __restrict__ i_l2g,
          const int* __restrict__ m_g2g, const int* __restrict__ m_g2l,
          const int* __restrict__ i_g2g, const int* __restrict__ i_g2l,
          u8* __restrict__ pkl, u8* __restrict__ pkg,
          const void* __restrict__ W0, const void* __restrict__ W1,
          const void* __restrict__ W2, const void* __restrict__ W3,
          const void* __restrict__ W4, const void* __restrict__ W5,
          const void* __restrict__ W6, const void* __restrict__ W7,
          u16* __restrict__ wtq, u16* __restrict__ wto,
          const void* __restrict__ xlin, const void* __restrict__ xgin,
          u16* __restrict__ xl, u16* __restrict__ xg,
          const void* __restrict__ embl, const void* __restrict__ rbl,
          const void* __restrict__ embg, const void* __restrict__ rbg,
          const void* __restrict__ bql, const void* __restrict__ bqg,
          u16* __restrict__ wtrel, float* __restrict__ crel,
          const int* __restrict__ flagp) {
  __shared__ u16 T[64][72];
  const bool f32m = (*flagp != 0);
  const int tid = threadIdx.x;
  const int bid = blockIdx.x;

  if (bid < PKL_BLK) {
    // ---- pack_l v2: [(b,n)][tile][qrow(128)][ln*4+kt] ----
    const unsigned idx = (unsigned)bid * 256u + tid;
    const int pos = idx & 63;
    const int lnp = pos >> 2, ktp = pos & 3;
    const int qrow = (idx >> 6) & 127;
    const unsigned rest = idx >> 13;
    const int tile = rest % 10;
    const unsigned bn = rest / 10;
    const int n = bn & 31, b = bn >> 5;
    const int c = (tile << 6) + (ktp << 4) + lnp;
    const unsigned bt = (unsigned)b * LL + (n << 7) + qrow;
    int mask = 0, id = 0;
    if (c < 384) {
      const int rr = c - qrow - 1;
      const int jabs = ((n - 1) << 7) + c;
      if (rr >= 0 && rr < WW && jabs >= 0 && jabs < LL) {
        const size_t base = (size_t)bt * WW + rr;
        mask = m_l2l[base]; id = i_l2l[base];
      }
    } else {
      const size_t base = (size_t)bt * GG + (c - 384);
      mask = m_l2g[base]; id = i_l2g[base];
    }
    pkl[idx] = (u8)((id & 31) | ((mask ^ 1) << 7));
  } else if (bid < PKL_BLK + PKG_BLK) {
    // ---- pack_g v3: [(b,qtp)][tl(68)][qrow(128)][ln*4+kt] ----
    const unsigned idx = (unsigned)(bid - PKL_BLK) * 256u + tid;
    const int pos = idx & 63;
    const int lnp = pos >> 2, ktp = pos & 3;
    const int qrow = (idx >> 6) & 127;
    const unsigned rest = idx >> 13;
    const int tl = rest % 68;
    const unsigned b2q = rest / 68;
    const int b = b2q >> 1, qtp = b2q & 1;
    const int c = (tl << 6) + (ktp << 4) + lnp;
    const int q = (qtp << 7) + qrow;
    int mask, id;
    if (c < 256) {
      const size_t base = ((size_t)b * GG + q) * GG + c;
      mask = m_g2g[base]; id = i_g2g[base];
    } else {
      const size_t base = ((size_t)b * GG + q) * (size_t)LL + (c - 256);
      mask = m_g2l[base]; id = i_g2l[base];
    }
    pkg[idx] = (u8)((id & 31) | ((mask ^ 1) << 7));
  } else if (bid < PKL_BLK + PKG_BLK + WPR_BLK) {
    // ---- wprep: Wt[n][k] = bf16(W[k][n]), 64x64 LDS-tiled; 8 mats ----
    const int blk = bid - (PKL_BLK + PKG_BLK);
    const int mat = blk / 144;
    const int rem = blk % 144;
    const int n0 = (rem % 12) << 6, k0 = (rem / 12) << 6;
    const void* Wm = (mat == 0) ? W0 : (mat == 1) ? W1 : (mat == 2) ? W2
                     : (mat == 3) ? W3 : (mat == 4) ? W4 : (mat == 5) ? W5
                     : (mat == 6) ? W6 : W7;
    u16* wbase = (mat < 6) ? (wtq + (size_t)mat * WMAT)
                           : (wto + (size_t)(mat - 6) * WMAT);
    {
      const int r = tid >> 2, c0 = (tid & 3) << 4;
      if (f32m) {
        const float* wp = reinterpret_cast<const float*>(Wm) + (size_t)(k0 + r) * 768 + n0 + c0;
        #pragma unroll
        for (int j = 0; j < 16; j += 4) {
          float4 v = *reinterpret_cast<const float4*>(wp + j);
          T[r][c0 + j + 0] = f2bf(v.x); T[r][c0 + j + 1] = f2bf(v.y);
          T[r][c0 + j + 2] = f2bf(v.z); T[r][c0 + j + 3] = f2bf(v.w);
        }
      } else {
        const u16* wp = reinterpret_cast<const u16*>(Wm) + (size_t)(k0 + r) * 768 + n0 + c0;
        *reinterpret_cast<int4*>(&T[r][c0]) = reinterpret_cast<const int4*>(wp)[0];
        *reinterpret_cast<int4*>(&T[r][c0 + 8]) = reinterpret_cast<const int4*>(wp)[1];
      }
    }
    __syncthreads();
    {
      const int n = tid >> 2, kc0 = (tid & 3) << 4;
      u16 buf[16];
      #pragma unroll
      for (int j = 0; j < 16; j++) buf[j] = T[kc0 + j][n];
      u16* op = wbase + (size_t)(n0 + n) * 768 + k0 + kc0;
      *reinterpret_cast<int4*>(op) = *reinterpret_cast<int4*>(buf);
      *reinterpret_cast<int4*>(op + 8) = *reinterpret_cast<int4*>(buf + 8);
    }
  } else if (bid < PKL_BLK + PKG_BLK + WPR_BLK + XPL_BLK + XPG_BLK) {
    // ---- xprep: f32->bf16 (or copy), 8 elems/thread ----
    const int blk = bid - (PKL_BLK + PKG_BLK + WPR_BLK);
    const void* src;
    u16* dst;
    size_t i;
    if (blk < XPL_BLK) {
      src = xlin; dst = xl;
      i = ((size_t)blk * 256 + tid) << 3;
    } else {
      src = xgin; dst = xg;
      i = ((size_t)(blk - XPL_BLK) * 256 + tid) << 3;
    }
    if (f32m) {
      const float* p = reinterpret_cast<const float*>(src) + i;
      float4 a = *reinterpret_cast<const float4*>(p);
      float4 b = *reinterpret_cast<const float4*>(p + 4);
      u16 o[8] = {f2bf(a.x), f2bf(a.y), f2bf(a.z), f2bf(a.w),
                  f2bf(b.x), f2bf(b.y), f2bf(b.z), f2bf(b.w)};
      *reinterpret_cast<int4*>(dst + i) = *reinterpret_cast<int4*>(o);
    } else {
      *reinterpret_cast<int4*>(dst + i) =
          *reinterpret_cast<const int4*>(reinterpret_cast<const u16*>(src) + i);
    }
  } else {
    // ---- M-prep: one block per (side, n=h*32+r) ----
    const int blk = bid - (PKL_BLK + PKG_BLK + WPR_BLK + XPL_BLK + XPG_BLK);
    const int side = blk / 384;          // 0=long, 1=glob
    const int nl = blk % 384;
    const int h = nl >> 5, r = nl & 31;
    const void* Wq = side ? W3 : W0;     // wq_g : wq_l
    const void* emb = side ? embg : embl;
    const void* bqv = side ? bqg : bql;
    const void* rbv = side ? rbg : rbl;
    float* ef = reinterpret_cast<float*>(&T[0][0]);
    if (tid < 64) ef[tid] = ldx1(emb, ((size_t)r * HH + h) * DD + tid, f32m);
    __syncthreads();
    #pragma unroll
    for (int ko = 0; ko < 3; ko++) {
      const int k = tid + (ko << 8);
      const size_t base = (size_t)k * 768 + h * 64;
      float a = 0.f;
      if (f32m) {
        const float* wp = reinterpret_cast<const float*>(Wq) + base;
        #pragma unroll
        for (int d = 0; d < 64; d += 4) {
          float4 v = *reinterpret_cast<const float4*>(wp + d);
          a += v.x * ef[d] + v.y * ef[d + 1] + v.z * ef[d + 2] + v.w * ef[d + 3];
        }
      } else {
        const u16* wp = reinterpret_cast<const u16*>(Wq) + base;
        #pragma unroll
        for (int d = 0; d < 64; d += 4) {
          float4 v = ld4bf(wp + d);
          a += v.x * ef[d] + v.y * ef[d + 1] + v.z * ef[d + 2] + v.w * ef[d + 3];
        }
      }
      wtrel[(size_t)side * MMAT + (size_t)nl * 768 + k] = f2bf(0.125f * a);
    }
    if (tid == 0) {
      float s = ldx1(rbv, (size_t)r * HH + h, f32m);
      for (int d = 0; d < 64; d++)
        s += ldx1(bqv, h * 64 + d, f32m) * ef[d];
      crel[side * 384 + nl] = 0.125f * s;
    }
  }
}

// =========================================================================
// m97-structure GEMM core: 128x128 tile, BK=64, 4 waves (2x2), single-buffer
// LDS staged via global_load_lds(16B) with T2 XOR swizzle.
// =========================================================================
#define GEMM_CORE(A_, Wt_, row0_, ncol0_)                                        \
  __shared__ u16 lds[16384];                                                     \
  const int tid = threadIdx.x;                                                   \
  const int w = tid >> 6, l = tid & 63;                                          \
  const int lm = l & 15, quad = l >> 4;                                          \
  const int wr = w >> 1, wc = w & 1;                                             \
  const int rb = (w << 5) + (l >> 3);                                            \
  const int c8 = (l & 7) ^ (l >> 3);                                             \
  const u16* asrc = A_ + (size_t)(row0_ + rb) * 768 + (c8 << 3);                 \
  const u16* bsrc = Wt_ + (size_t)(ncol0_ + rb) * 768 + (c8 << 3);               \
  u16* adst = lds + (w << 11) + (l << 3);                                        \
  u16* bdst = adst + 8192;                                                       \
  f32x4 acc[4][4];                                                               \
  _Pragma("unroll")                                                              \
  for (int mt = 0; mt < 4; mt++)                                                 \
    _Pragma("unroll")                                                            \
    for (int nt = 0; nt < 4; nt++) acc[mt][nt] = (f32x4){0.f, 0.f, 0.f, 0.f};    \
  const char* abase = reinterpret_cast<const char*>(lds);                        \
  const char* bbase = abase + 16384;                                             \
  const int xorv = (lm & 7) << 4;                                                \
  for (int k0 = 0; k0 < 768; k0 += 64) {                                         \
    __syncthreads();                                                             \
    _Pragma("unroll")                                                            \
    for (int i = 0; i < 4; i++) gload16(asrc + k0 + i * 6144, adst + (i << 9));  \
    _Pragma("unroll")                                                            \
    for (int i = 0; i < 4; i++) gload16(bsrc + k0 + i * 6144, bdst + (i << 9));  \
    __syncthreads();                                                             \
    _Pragma("unroll")                                                            \
    for (int kk = 0; kk < 2; kk++) {                                             \
      bf16x8 af[4], bfr[4];                                                      \
      _Pragma("unroll")                                                          \
      for (int mt = 0; mt < 4; mt++)                                             \
        af[mt] = *reinterpret_cast<const bf16x8*>(                               \
            abase + ((wr << 6) + (mt << 4) + lm) * 128 +                         \
            (((kk << 6) + (quad << 4)) ^ xorv));                                 \
      _Pragma("unroll")                                                          \
      for (int nt = 0; nt < 4; nt++)                                             \
        bfr[nt] = *reinterpret_cast<const bf16x8*>(                              \
            bbase + ((wc << 6) + (nt << 4) + lm) * 128 +                         \
            (((kk << 6) + (quad << 4)) ^ xorv));                                 \
      _Pragma("unroll")                                                          \
      for (int mt = 0; mt < 4; mt++)                                             \
        _Pragma("unroll")                                                        \
        for (int nt = 0; nt < 4; nt++)                                           \
          acc[mt][nt] = __builtin_amdgcn_mfma_f32_16x16x32_bf16(                 \
              af[mt], bfr[nt], acc[mt][nt], 0, 0, 0);                            \
    }                                                                            \
  }

// ---------- fused QKV+rel GEMM, long U glob in one launch (1428 blocks) ----------
// lx 0..17 -> Q/K/V columns (Wt); lx 18..20 -> rel columns (Mt fold).
__global__ __launch_bounds__(256)
void gemm_qkv(const u16* __restrict__ Al, const u16* __restrict__ Ag,
              const u16* __restrict__ Wtq, const u16* __restrict__ Wtr,
              const float* __restrict__ crel,
              const void* __restrict__ bql, const void* __restrict__ bkl,
              const void* __restrict__ bvl,
              const void* __restrict__ bqg, const void* __restrict__ bkg,
              const void* __restrict__ bvg,
              u16* __restrict__ lq, u16* __restrict__ lk, u16* __restrict__ lv,
              u16* __restrict__ gq, u16* __restrict__ gk, u16* __restrict__ gv,
              u16* __restrict__ rell, u16* __restrict__ relg,
              const int* __restrict__ flagp) {
  const bool f32m = (*flagp != 0);
  const int fid = blockIdx.x;
  int lx, ly;
  bool isL;
  if (fid < 1344) {          // long, XCD-swizzled: XCD x owns ly in [8x,8x+8)
    isL = true;
    const int x = fid & 7, rr = fid >> 3;
    ly = (x << 3) | (rr & 7);
    lx = rr >> 3;
  } else {                   // glob
    isL = false;
    const int g = fid - 1344;
    lx = g % 21; ly = g / 21;
  }
  const u16* A = isL ? Al : Ag;
  const u16* Wsel;
  int ncolw;
  if (lx < 18) { Wsel = isL ? Wtq : (Wtq + (size_t)3 * WMAT); ncolw = lx << 7; }
  else         { Wsel = Wtr + (isL ? 0 : (size_t)MMAT);       ncolw = (lx - 18) << 7; }
  const int row0 = ly << 7;
  GEMM_CORE(A, Wsel, row0, ncolw)

  if (lx < 18) {
    const int which = lx / 6;
    const void* bias = (which == 0) ? (isL ? bql : bqg)
                     : (which == 1) ? (isL ? bkl : bkg) : (isL ? bvl : bvg);
    u16* Cv = (which == 0) ? (isL ? lq : gq)
            : (which == 1) ? (isL ? lk : gk) : (isL ? lv : gv);
    const float sc = (which == 0) ? 0.125f : 1.0f;   // fold softmax scale into Q
    const int colw = (lx % 6) << 7;
    #pragma unroll
    for (int nt = 0; nt < 4; nt++) {
      const int gcol = colw + (wc << 6) + (nt << 4) + lm;
      const float bv = ldx1(bias, gcol, f32m);
      #pragma unroll
      for (int mt = 0; mt < 4; mt++)
        #pragma unroll
        for (int r = 0; r < 4; r++) {
          const int grow = row0 + (wr << 6) + (mt << 4) + (quad << 2) + r;
          Cv[(size_t)grow * 768 + gcol] = f2bf((acc[mt][nt][r] + bv) * sc);
        }
    }
  } else {
    const float* cr = crel + (isL ? 0 : 384);
    u16* ro = isL ? rell : relg;
    #pragma unroll
    for (int nt = 0; nt < 4; nt++) {
      const int gcol = ncolw + (wc << 6) + (nt << 4) + lm;
      const float cv = cr[gcol];
      #pragma unroll
      for (int mt = 0; mt < 4; mt++)
        #pragma unroll
        for (int r = 0; r < 4; r++) {
          const int grow = row0 + (wr << 6) + (mt << 4) + (quad << 2) + r;
          ro[(size_t)grow * 384 + gcol] = f2bf(acc[mt][nt][r] + cv);
        }
    }
  }
}

// ---------- output-projection GEMM, long U glob (408 blocks) ----------
__global__ __launch_bounds__(256)
void gemm_out(const u16* __restrict__ Alc, const u16* __restrict__ Agc,
              const u16* __restrict__ Wto,
              const void* __restrict__ bol, const void* __restrict__ bog,
              void* __restrict__ Cv, const int* __restrict__ flagp) {
  const bool f32m = (*flagp != 0);
  const int fid = blockIdx.x;
  int lx, ly;
  const u16 *A, *Wt;
  const void* bias;
  size_t c_off;
  if (fid < 384) {           // long, XCD-swizzled
    const int x = fid & 7, r = fid >> 3;
    ly = (x << 3) | (r & 7);
    lx = r >> 3;
    A = Alc; Wt = Wto; bias = bol; c_off = 0;
  } else {
    const int g = fid - 384;
    lx = g % 6; ly = g / 6;
    A = Agc; Wt = Wto + WMAT; bias = bog; c_off = (size_t)BB * LL * 768;
  }
  const int row0 = ly << 7;
  const int ncol0 = lx << 7;
  GEMM_CORE(A, Wt, row0, ncol0)

  #pragma unroll
  for (int nt = 0; nt < 4; nt++) {
    const int gcol = ncol0 + (wc << 6) + (nt << 4) + lm;
    const float bv = ldx1(bias, gcol, f32m);
    #pragma unroll
    for (int mt = 0; mt < 4; mt++)
      #pragma unroll
      for (int r = 0; r < 4; r++) {
        const int grow = row0 + (wr << 6) + (mt << 4) + (quad << 2) + r;
        const float v = acc[mt][nt][r] + bv;
        if (f32m)
          reinterpret_cast<float*>(Cv)[c_off + (size_t)grow * 768 + gcol] = v;
        else
          reinterpret_cast<u16*>(Cv)[c_off + (size_t)grow * 768 + gcol] = f2bf(v);
      }
  }
}

// ---------- long-token attention: 128-query block, 512 threads ----------
// sigma-permuted contraction dim for P/V: sigma(k) = (k&15)*4 + (k>>4).
// P stored via v_cvt_pk_bf16_f32 pairs; V written at sigma(col); PV MFMA
// reads the same sigma-window from both operands. (Verified rounds 6-9.)
__global__ __launch_bounds__(512)
void lattn(const u16* __restrict__ lq, const u16* __restrict__ lk, const u16* __restrict__ lv,
           const u16* __restrict__ gk, const u16* __restrict__ gv,
           const u32* __restrict__ pkl, const u16* __restrict__ rel,
           u16* __restrict__ lctx) {
  const int fid = blockIdx.x + 12 * (blockIdx.y + (blockIdx.z << 5));
  const int hg = fid >> 3;                       // 0..95
  const int h = hg % 12;
  const int fl = (fid & 7) + ((hg / 12) << 3);   // 0..63 = b*32+n
  const int n = fl & 31, b = fl >> 5;
  const int tid = threadIdx.x;
  __shared__ u16 Kt[64][72];    // [k][d]
  __shared__ u16 Vt[64][74];    // [d][sigma(k)]
  __shared__ u16 Pt[128][76];   // [q][sigma(k)]
  __shared__ u16 Rl[128][36];   // per-q rel row (32 bf16, pre-scaled)

  const int lane = tid & 63, wv = tid >> 6;      // wv 0..7
  const int ln = lane & 15, quad = lane >> 4;
  const int tbase = n << 7;

  {
    const int qr = (wv << 4) + (lane >> 2);
    const int seg = (lane & 3) << 3;
    *reinterpret_cast<int4*>(&Rl[qr][seg]) = *reinterpret_cast<const int4*>(
        rel + ((size_t)(b * LL + tbase + qr)) * 384 + h * 32 + seg);
  }

  bf16x8 aq[2];
  {
    const int t = tbase + (wv << 4) + ln;
    const u16* qp = lq + (((size_t)b * LL + t) * HH + h) * DD + (quad << 3);
    aq[0] = *reinterpret_cast<const bf16x8*>(qp);
    aq[1] = *reinterpret_cast<const bf16x8*>(qp + 32);
  }

  const u32* pk32 = pkl + (size_t)(b * 32 + n) * 20480;   // 10*128*16 u32
  const int skey = tid >> 3, sdg = (tid & 7) << 3;
  const int scol = ((skey & 15) << 2) | (skey >> 4);      // sigma(skey)

  f32x4 Oacc[4];
  #pragma unroll
  for (int dt = 0; dt < 4; dt++) Oacc[dt] = (f32x4){0.f, 0.f, 0.f, 0.f};
  float lpart[4] = {};

  for (int tile = 0; tile < 10; tile++) {
    const int c0 = tile << 6;
    const bool isg = (tile >= 6);

    // badd: 4 coalesced u32 loads + LDS gather + cndmask
    float badd[16];
    #pragma unroll
    for (int r = 0; r < 4; r++) {
      const int qrow = (wv << 4) + (quad << 2) + r;
      const u32 pw = pk32[(((tile << 7) + qrow) << 4) + ln];
      #pragma unroll
      for (int kt = 0; kt < 4; kt++) {
        const u32 pb = (pw >> (kt << 3)) & 0xFFu;
        const float rv = bf2f(Rl[qrow][pb & 31]);
        badd[(kt << 2) + r] = (pb & 0x80u) ? (rv - 10000.f) : rv;
      }
    }

    __syncthreads();
    {
      int4 kraw = {0, 0, 0, 0}, vraw = {0, 0, 0, 0};
      if (isg) {
        const size_t base = (((size_t)b * GG + (c0 - 384) + skey) * HH + h) * DD + sdg;
        kraw = *reinterpret_cast<const int4*>(gk + base);
        vraw = *reinterpret_cast<const int4*>(gv + base);
      } else {
        const int jabs = ((n - 1) << 7) + c0 + skey;
        if (jabs >= 0 && jabs < LL) {
          const size_t base = (((size_t)b * LL + jabs) * HH + h) * DD + sdg;
          kraw = *reinterpret_cast<const int4*>(lk + base);
          vraw = *reinterpret_cast<const int4*>(lv + base);
        }
      }
      *reinterpret_cast<int4*>(&Kt[skey][sdg]) = kraw;
      u16 vb[8];
      *reinterpret_cast<int4*>(vb) = vraw;
      #pragma unroll
      for (int j = 0; j < 8; j++) Vt[sdg + j][scol] = vb[j];
    }
    __syncthreads();

    f32x4 Sacc[4];
    #pragma unroll
    for (int kt = 0; kt < 4; kt++) Sacc[kt] = (f32x4){0.f, 0.f, 0.f, 0.f};
    __builtin_amdgcn_s_setprio(1);
    #pragma unroll
    for (int kk = 0; kk < 2; kk++) {
      bf16x8 bk[4];
      #pragma unroll
      for (int kt = 0; kt < 4; kt++)
        bk[kt] = *reinterpret_cast<const bf16x8*>(&Kt[(kt << 4) + ln][(kk << 5) + (quad << 3)]);
      #pragma unroll
      for (int kt = 0; kt < 4; kt++)
        Sacc[kt] = __builtin_amdgcn_mfma_f32_16x16x32_bf16(aq[kk], bk[kt], Sacc[kt], 0, 0, 0);
    }
    __builtin_amdgcn_s_setprio(0);

    // softmax + packed P store (lane's k's = kt*16+ln -> sigma cols 4ln..4ln+3)
    #pragma unroll
    for (int r = 0; r < 4; r++) {
      const int ql = (wv << 4) + (quad << 2) + r;
      const float p0 = __expf(Sacc[0][r] + badd[0 + r]);
      const float p1 = __expf(Sacc[1][r] + badd[4 + r]);
      const float p2 = __expf(Sacc[2][r] + badd[8 + r]);
      const float p3 = __expf(Sacc[3][r] + badd[12 + r]);
      u32 w0, w1;
      asm("v_cvt_pk_bf16_f32 %0, %1, %2" : "=v"(w0) : "v"(p0), "v"(p1));
      asm("v_cvt_pk_bf16_f32 %0, %1, %2" : "=v"(w1) : "v"(p2), "v"(p3));
      uint2 wp; wp.x = w0; wp.y = w1;
      *reinterpret_cast<uint2*>(&Pt[ql][ln << 2]) = wp;
      lpart[r] += (p0 + p1) + (p2 + p3);
    }

    __builtin_amdgcn_s_setprio(1);
    #pragma unroll
    for (int kk = 0; kk < 2; kk++) {
      bf16x8 ap = *reinterpret_cast<const bf16x8*>(&Pt[(wv << 4) + ln][(kk << 5) + (quad << 3)]);
      #pragma unroll
      for (int dt = 0; dt < 4; dt++) {
        bf16x8 bv = *reinterpret_cast<const bf16x8*>(&Vt[(dt << 4) + ln][(kk << 5) + (quad << 3)]);
        Oacc[dt] = __builtin_amdgcn_mfma_f32_16x16x32_bf16(ap, bv, Oacc[dt], 0, 0, 0);
      }
    }
    __builtin_amdgcn_s_setprio(0);
  }

  #pragma unroll
  for (int r = 0; r < 4; r++) {
    float v = lpart[r];
    v += __shfl_xor(v, 1); v += __shfl_xor(v, 2);
    v += __shfl_xor(v, 4); v += __shfl_xor(v, 8);
    const float inv = 1.0f / v;
    const int t = tbase + (wv << 4) + (quad << 2) + r;
    const size_t base = (((size_t)b * LL + t) * HH + h) * DD;
    #pragma unroll
    for (int dt = 0; dt < 4; dt++)
      lctx[base + (dt << 4) + ln] = f2bf(Oacc[dt][r] * inv);
  }
}

// ---------- global-token attention: qt-pair merged, 512 threads ----------
__global__ __launch_bounds__(512)
void gattn(const u16* __restrict__ gq, const u16* __restrict__ gk, const u16* __restrict__ gv,
           const u16* __restrict__ lk, const u16* __restrict__ lv,
           const u32* __restrict__ pkg, const u16* __restrict__ relg,
           float* __restrict__ po, float* __restrict__ pl) {
  const int fid = blockIdx.x;
  const int x = fid & 7;
  const int slot = fid >> 3;            // 0..101
  const int qtp = slot & 1;
  const int g = ((slot >> 1) << 3) | x; // 0..407
  const int h = g % 12;
  const int cb = g / 12;                // 0..33
  const int chunk = cb % 17;
  const int b = cb / 17;
  const int tid = threadIdx.x;
  __shared__ u16 Kt[64][72];
  __shared__ u16 Vt[64][74];
  __shared__ u16 Pt[128][76];
  __shared__ u16 Rg[128][36];

  const int lane = tid & 63, wv = tid >> 6;      // wv 0..7
  const int ln = lane & 15, quad = lane >> 4;
  const int qbase = qtp << 7;
  const int kbase = chunk << 8;
  const bool isgg = (chunk == 0);

  {
    const int qr = (wv << 4) + (lane >> 2);
    const int seg = (lane & 3) << 3;
    *reinterpret_cast<int4*>(&Rg[qr][seg]) = *reinterpret_cast<const int4*>(
        relg + ((size_t)(b * GG + qbase + qr)) * 384 + h * 32 + seg);
  }

  bf16x8 aq[2];
  {
    const int qa = qbase + (wv << 4) + ln;
    const u16* qp = gq + (((size_t)b * GG + qa) * HH + h) * DD + (quad << 3);
    aq[0] = *reinterpret_cast<const bf16x8*>(qp);
    aq[1] = *reinterpret_cast<const bf16x8*>(qp + 32);
  }

  const u32* pk32 = pkg + (size_t)((b << 1) + qtp) * 139264;  // 68*128*16 u32
  const int skey = tid >> 3, sdg = (tid & 7) << 3;
  const int scol = ((skey & 15) << 2) | (skey >> 4);          // sigma(skey)

  f32x4 Oacc[4];
  #pragma unroll
  for (int dt = 0; dt < 4; dt++) Oacc[dt] = (f32x4){0.f, 0.f, 0.f, 0.f};
  float lpart[4] = {};

  for (int tile = 0; tile < 4; tile++) {
    const int tl = (chunk << 2) + tile;

    float badd[16];
    #pragma unroll
    for (int r = 0; r < 4; r++) {
      const int qrow = (wv << 4) + (quad << 2) + r;
      const u32 pw = pk32[(((tl << 7) + qrow) << 4) + ln];
      #pragma unroll
      for (int kt = 0; kt < 4; kt++) {
        const u32 pb = (pw >> (kt << 3)) & 0xFFu;
        const float rv = bf2f(Rg[qrow][pb & 31]);
        badd[(kt << 2) + r] = (pb & 0x80u) ? (rv - 10000.f) : rv;
      }
    }

    __syncthreads();
    {
      const int kc = kbase + (tile << 6) + skey;
      int4 kraw, vraw;
      if (isgg) {
        const size_t base = (((size_t)b * GG + kc) * HH + h) * DD + sdg;
        kraw = *reinterpret_cast<const int4*>(gk + base);
        vraw = *reinterpret_cast<const int4*>(gv + base);
      } else {
        const size_t base = (((size_t)b * LL + (kc - 256)) * HH + h) * DD + sdg;
        kraw = *reinterpret_cast<const int4*>(lk + base);
        vraw = *reinterpret_cast<const int4*>(lv + base);
      }
      *reinterpret_cast<int4*>(&Kt[skey][sdg]) = kraw;
      u16 vb[8];
      *reinterpret_cast<int4*>(vb) = vraw;
      #pragma unroll
      for (int j = 0; j < 8; j++) Vt[sdg + j][scol] = vb[j];
    }
    __syncthreads();

    f32x4 Sacc[4];
    #pragma unroll
    for (int kt = 0; kt < 4; kt++) Sacc[kt] = (f32x4){0.f, 0.f, 0.f, 0.f};
    __builtin_amdgcn_s_setprio(1);
    #pragma unroll
    for (int kk = 0; kk < 2; kk++) {
      bf16x8 bk[4];
      #pragma unroll
      for (int kt = 0; kt < 4; kt++)
        bk[kt] = *reinterpret_cast<const bf16x8*>(&Kt[(kt << 4) + ln][(kk << 5) + (quad << 3)]);
      #pragma unroll
      for (int kt = 0; kt < 4; kt++)
        Sacc[kt] = __builtin_amdgcn_mfma_f32_16x16x32_bf16(aq[kk], bk[kt], Sacc[kt], 0, 0, 0);
    }
    __builtin_amdgcn_s_setprio(0);

    #pragma unroll
    for (int r = 0; r < 4; r++) {
      const int ql = (wv << 4) + (quad << 2) + r;
      const float p0 = __expf(Sacc[0][r] + badd[0 + r]);
      const float p1 = __expf(Sacc[1][r] + badd[4 + r]);
      const float p2 = __expf(Sacc[2][r] + badd[8 + r]);
      const float p3 = __expf(Sacc[3][r] + badd[12 + r]);
      u32 w0, w1;
      asm("v_cvt_pk_bf16_f32 %0, %1, %2" : "=v"(w0) : "v"(p0), "v"(p1));
      asm("v_cvt_pk_bf16_f32 %0, %1, %2" : "=v"(w1) : "v"(p2), "v"(p3));
      uint2 wp; wp.x = w0; wp.y = w1;
      *reinterpret_cast<uint2*>(&Pt[ql][ln << 2]) = wp;
      lpart[r] += (p0 + p1) + (p2 + p3);
    }

    __builtin_amdgcn_s_setprio(1);
    #pragma unroll
    for (int kk = 0; kk < 2; kk++) {
      bf16x8 ap = *reinterpret_cast<const bf16x8*>(&Pt[(wv << 4) + ln][(kk << 5) + (quad << 3)]);
      #pragma unroll
      for (int dt = 0; dt < 4; dt++) {
        bf16x8 bv = *reinterpret_cast<const bf16x8*>(&Vt[(dt << 4) + ln][(kk << 5) + (quad << 3)]);
        Oacc[dt] = __builtin_amdgcn_mfma_f32_16x16x32_bf16(ap, bv, Oacc[dt], 0, 0, 0);
      }
    }
    __builtin_amdgcn_s_setprio(0);
  }

  #pragma unroll
  for (int r = 0; r < 4; r++) {
    float v = lpart[r];
    v += __shfl_xor(v, 1); v += __shfl_xor(v, 2);
    v += __shfl_xor(v, 4); v += __shfl_xor(v, 8);
    const int qa = qbase + (wv << 4) + (quad << 2) + r;
    if (ln == 0)
      pl[(((size_t)chunk * BB + b) * HH + h) * GG + qa] = v;
    const size_t base = ((((size_t)chunk * BB + b) * HH + h) * GG + qa) * DD;
    #pragma unroll
    for (int dt = 0; dt < 4; dt++)
      po[base + (dt << 4) + ln] = Oacc[dt][r];
  }
}

// ---------- combine global-attention partials (17 chunks) ----------
__global__ __launch_bounds__(256)
void gcombine(const float* __restrict__ po, const float* __restrict__ pl,
              u16* __restrict__ gctx) {
  const int flat = blockIdx.x * 256 + threadIdx.x;
  const int d = flat & 63;
  const int rest = flat >> 6;
  const int h = rest % HH;
  const int bq = rest / HH;
  const int b = bq >> 8, qg = bq & 255;
  float so = 0.f, sl = 0.f;
  #pragma unroll
  for (int c = 0; c < NCHUNK; c++) {
    so += po[((((size_t)c * BB + b) * HH + h) * GG + qg) * DD + d];
    sl += pl[(((size_t)c * BB + b) * HH + h) * GG + qg];
  }
  gctx[flat] = f2bf(so / sl);
}

// ---------- host launch ----------
extern "C" void kernel_launch(void* const* d_in, const int* in_sizes, int n_in,
                              void* d_out, int out_size, void* d_ws, size_t ws_size,
                              hipStream_t stream) {
  (void)in_sizes; (void)n_in; (void)out_size; (void)ws_size;
  const void* x_long = d_in[0];
  const void* x_glob = d_in[1];
  const int* m_l2l = (const int*)d_in[2];
  const int* m_g2g = (const int*)d_in[3];
  const int* m_l2g = (const int*)d_in[4];
  const int* m_g2l = (const int*)d_in[5];
  const int* i_l2l = (const int*)d_in[6];
  const int* i_g2g = (const int*)d_in[7];
  const int* i_l2g = (const int*)d_in[8];
  const int* i_g2l = (const int*)d_in[9];
  const void* wq_l = d_in[10]; const void* bq_l = d_in[11];
  const void* wk_l = d_in[12]; const void* bk_l = d_in[13];
  const void* wv_l = d_in[14]; const void* bv_l = d_in[15];
  const void* wq_g = d_in[16]; const void* bq_g = d_in[17];
  const void* wk_g = d_in[18]; const void* bk_g = d_in[19];
  const void* wv_g = d_in[20]; const void* bv_g = d_in[21];
  const void* rel_emb_l = d_in[22]; const void* rel_bias_l = d_in[23];
  const void* rel_emb_g = d_in[24]; const void* rel_bias_g = d_in[25];
  const void* wo_l = d_in[26]; const void* bo_l = d_in[27];
  const void* wo_g = d_in[28]; const void* bo_g = d_in[29];

  constexpr size_t NLQ = (size_t)BB * LL * HH * DD;
  constexpr size_t NG  = (size_t)BB * GG * HH * DD;
  constexpr size_t NRL = (size_t)BB * LL * HH * VV;
  constexpr size_t NRG = (size_t)BB * GG * HH * VV;
  u16* lqw  = reinterpret_cast<u16*>(d_ws);
  u16* lkw  = lqw + NLQ;
  u16* lvw  = lkw + NLQ;
  u16* gqw  = lvw + NLQ;
  u16* gkw  = gqw + NG;
  u16* gvw  = gkw + NG;
  u16* rell = gvw + NG;
  u16* relg = rell + NRL;
  u16* lctx = relg + NRG;
  u16* gctx = lctx + NLQ;
  int* flag = reinterpret_cast<int*>(gctx + NG);
  float* po = reinterpret_cast<float*>(flag + 16);          // [17][B][H][G][D]
  float* pl = po + (size_t)NCHUNK * BB * HH * GG * DD;      // [17][B][H][G]
  // Overlays (same-stream liveness):
  //  pk_l   -> po base      (dead once lattn finishes; gattn writes po after)
  //  wt_qkv -> po + 5.24 MB (dead once gemm_qkv finishes)
  //  xl_bf  -> lctx region  (dead once gemm_qkv finishes)
  //  xg_bf  -> gctx region  (dead once gemm_qkv finishes)
  u8* pk_l = reinterpret_cast<u8*>(po);                     // [B*32][10][128][64]
  u16* wt_qkv = reinterpret_cast<u16*>(po) + 2621440;       // 6 mats x WMAT
  u16* xl_bf = lctx;
  u16* xg_bf = gctx;
  u8* pk_g = reinterpret_cast<u8*>(pl + (size_t)NCHUNK * BB * HH * GG);  // [B*2][68][128][64]
  u16* wt_o = reinterpret_cast<u16*>(pk_g + (size_t)BB * GG * GKEY);     // 2 mats x WMAT
  u16* wt_rel = wt_o + (size_t)2 * WMAT;                    // 2 x [384][768] bf16
  float* c_rel = reinterpret_cast<float*>(wt_rel + (size_t)2 * MMAT);    // [768] f32

  dim3 t256(256);
  detect_dtype<<<1, t256, 0, stream>>>(x_long, flag);
  prep<<<dim3(PKL_BLK + PKG_BLK + WPR_BLK + XPL_BLK + XPG_BLK + MPR_BLK), t256, 0, stream>>>(
      m_l2l, m_l2g, i_l2l, i_l2g, m_g2g, m_g2l, i_g2g, i_g2l, pk_l, pk_g,
      wq_l, wk_l, wv_l, wq_g, wk_g, wv_g, wo_l, wo_g, wt_qkv, wt_o,
      x_long, x_glob, xl_bf, xg_bf,
      rel_emb_l, rel_bias_l, rel_emb_g, rel_bias_g, bq_l, bq_g,
      wt_rel, c_rel, flag);
  gemm_qkv<<<dim3(1428), t256, 0, stream>>>(
      xl_bf, xg_bf, wt_qkv, wt_rel, c_rel,
      bq_l, bk_l, bv_l, bq_g, bk_g, bv_g,
      lqw, lkw, lvw, gqw, gkw, gvw, rell, relg, flag);
  lattn<<<dim3(12, 32, 2), dim3(512), 0, stream>>>(lqw, lkw, lvw, gkw, gvw,
                                                   reinterpret_cast<const u32*>(pk_l), rell, lctx);
  gattn<<<dim3(816), dim3(512), 0, stream>>>(gqw, gkw, gvw, lkw, lvw,
                                             reinterpret_cast<const u32*>(pk_g), relg, po, pl);
  gcombine<<<dim3(1536), t256, 0, stream>>>(po, pl, gctx);
  gemm_out<<<dim3(408), t256, 0, stream>>>(lctx, gctx, wt_o, bo_l, bo_g, d_out, flag);
}

// Round 11
// 373.409 us; speedup vs baseline: 1.0737x; 1.0737x over previous
//
#include <hip/hip_runtime.h>
#include <hip/hip_bf16.h>

typedef unsigned short u16;
typedef unsigned char u8;
typedef unsigned int u32;
typedef __attribute__((ext_vector_type(8))) short bf16x8;
typedef __attribute__((ext_vector_type(4))) float f32x4;

#define BB 2
#define LL 4096
#define GG 256
#define HH 12
#define DD 64
#define NB 32
#define WW 255
#define VV 32
#define NCHUNK 17
#define LKEY 640      // 384 local-window keys + 256 global keys
#define GKEY 4352     // 256 global keys + 4096 long keys
#define WMAT 589824   // 768*768 elements per weight matrix
#define MMAT 294912   // 384*768 elements per rel-fold matrix

// prep-kernel block ranges
#define PKL_BLK 20480   // BB*LL*LKEY/256
#define PKG_BLK 8704    // BB*2*68*128*64/256
#define WPR_BLK 1152    // 12*12*8
#define XPL_BLK 3072    // BB*LL*768/2048
#define XPG_BLK 192     // BB*GG*768/2048
#define MPR_BLK 144     // 2 sides * 12 h * 6 ksplit

// ---------- bf16 helpers ----------
__device__ __forceinline__ float bf2f(u16 u) {
  return __uint_as_float(((unsigned)u) << 16);
}
__device__ __forceinline__ u16 f2bf(float f) {
  unsigned u = __float_as_uint(f);
  u += 0x7FFFu + ((u >> 16) & 1u);
  return (u16)(u >> 16);
}
__device__ __forceinline__ float4 ld4bf(const u16* p) {
  ushort4 q = *reinterpret_cast<const ushort4*>(p);
  return make_float4(bf2f(q.x), bf2f(q.y), bf2f(q.z), bf2f(q.w));
}
__device__ __forceinline__ float ldx1(const void* p, size_t idx, bool f32m) {
  if (f32m) return reinterpret_cast<const float*>(p)[idx];
  return bf2f(reinterpret_cast<const u16*>(p)[idx]);
}
// async global->LDS, 16B per lane; dest is wave-uniform base + lane*16
__device__ __forceinline__ void gload16(const u16* src, u16* ldsdst) {
  __builtin_amdgcn_global_load_lds(
      (const __attribute__((address_space(1))) unsigned int*)src,
      (__attribute__((address_space(3))) unsigned int*)ldsdst, 16, 0, 0);
}

// ---------- dtype detector (bf16 N(0,1) never has exponent >= 134) ----------
__global__ void detect_dtype(const void* __restrict__ x, int* __restrict__ flag) {
  __shared__ int cnt;
  if (threadIdx.x == 0) cnt = 0;
  __syncthreads();
  const u16* p = reinterpret_cast<const u16*>(x);
  int c = 0;
  for (int i = threadIdx.x; i < 4096; i += 256) {
    int e = (p[i] >> 7) & 0xFF;
    if (e >= 134) c++;
  }
  atomicAdd(&cnt, c);
  __syncthreads();
  if (threadIdx.x == 0) *flag = (cnt >= 64) ? 1 : 0;
}

// =========================================================================
// prep: pack_l U pack_g U wprep(8 mats) U xprep U M-prep, one launch.
// M-prep (LDS-tiled): Mt[n=h*32+r][k] = 0.125*sum_d Wq[k][h*64+d]*emb[r][h][d]
//   crel[n] = 0.125*(sum_d bq[h*64+d]*emb[r][h][d] + rel_bias[r][h])
// so rel_all = x . Mt^T + crel (folds the relk kernel into the QKV GEMM).
// =========================================================================
__global__ __launch_bounds__(256)
void prep(const int* __restrict__ m_l2l, const int* __restrict__ m_l2g,
          const int* __restrict__ i_l2l, const int* __restrict__ i_l2g,
          const int* __restrict__ m_g2g, const int* __restrict__ m_g2l,
          const int* __restrict__ i_g2g, const int* __restrict__ i_g2l,
          u8* __restrict__ pkl, u8* __restrict__ pkg,
          const void* __restrict__ W0, const void* __restrict__ W1,
          const void* __restrict__ W2, const void* __restrict__ W3,
          const void* __restrict__ W4, const void* __restrict__ W5,
          const void* __restrict__ W6, const void* __restrict__ W7,
          u16* __restrict__ wtq, u16* __restrict__ wto,
          const void* __restrict__ xlin, const void* __restrict__ xgin,
          u16* __restrict__ xl, u16* __restrict__ xg,
          const void* __restrict__ embl, const void* __restrict__ rbl,
          const void* __restrict__ embg, const void* __restrict__ rbg,
          const void* __restrict__ bql, const void* __restrict__ bqg,
          u16* __restrict__ wtrel, float* __restrict__ crel,
          const int* __restrict__ flagp) {
  __shared__ float SH[6720];   // 26.9 KB: Ef[32][68] | Wf[64][68] | bqf[64] | rbf[32]
  const bool f32m = (*flagp != 0);
  const int tid = threadIdx.x;
  const int bid = blockIdx.x;

  if (bid < PKL_BLK) {
    // ---- pack_l v2: [(b,n)][tile][qrow(128)][ln*4+kt] ----
    const unsigned idx = (unsigned)bid * 256u + tid;
    const int pos = idx & 63;
    const int lnp = pos >> 2, ktp = pos & 3;
    const int qrow = (idx >> 6) & 127;
    const unsigned rest = idx >> 13;
    const int tile = rest % 10;
    const unsigned bn = rest / 10;
    const int n = bn & 31, b = bn >> 5;
    const int c = (tile << 6) + (ktp << 4) + lnp;
    const unsigned bt = (unsigned)b * LL + (n << 7) + qrow;
    int mask = 0, id = 0;
    if (c < 384) {
      const int rr = c - qrow - 1;
      const int jabs = ((n - 1) << 7) + c;
      if (rr >= 0 && rr < WW && jabs >= 0 && jabs < LL) {
        const size_t base = (size_t)bt * WW + rr;
        mask = m_l2l[base]; id = i_l2l[base];
      }
    } else {
      const size_t base = (size_t)bt * GG + (c - 384);
      mask = m_l2g[base]; id = i_l2g[base];
    }
    pkl[idx] = (u8)((id & 31) | ((mask ^ 1) << 7));
  } else if (bid < PKL_BLK + PKG_BLK) {
    // ---- pack_g v3: [(b,qtp)][tl(68)][qrow(128)][ln*4+kt] ----
    const unsigned idx = (unsigned)(bid - PKL_BLK) * 256u + tid;
    const int pos = idx & 63;
    const int lnp = pos >> 2, ktp = pos & 3;
    const int qrow = (idx >> 6) & 127;
    const unsigned rest = idx >> 13;
    const int tl = rest % 68;
    const unsigned b2q = rest / 68;
    const int b = b2q >> 1, qtp = b2q & 1;
    const int c = (tl << 6) + (ktp << 4) + lnp;
    const int q = (qtp << 7) + qrow;
    int mask, id;
    if (c < 256) {
      const size_t base = ((size_t)b * GG + q) * GG + c;
      mask = m_g2g[base]; id = i_g2g[base];
    } else {
      const size_t base = ((size_t)b * GG + q) * (size_t)LL + (c - 256);
      mask = m_g2l[base]; id = i_g2l[base];
    }
    pkg[idx] = (u8)((id & 31) | ((mask ^ 1) << 7));
  } else if (bid < PKL_BLK + PKG_BLK + WPR_BLK) {
    // ---- wprep: Wt[n][k] = bf16(W[k][n]), 64x64 LDS-tiled; 8 mats ----
    u16* T16 = reinterpret_cast<u16*>(SH);       // [64][72] u16
    const int blk = bid - (PKL_BLK + PKG_BLK);
    const int mat = blk / 144;
    const int rem = blk % 144;
    const int n0 = (rem % 12) << 6, k0 = (rem / 12) << 6;
    const void* Wm = (mat == 0) ? W0 : (mat == 1) ? W1 : (mat == 2) ? W2
                     : (mat == 3) ? W3 : (mat == 4) ? W4 : (mat == 5) ? W5
                     : (mat == 6) ? W6 : W7;
    u16* wbase = (mat < 6) ? (wtq + (size_t)mat * WMAT)
                           : (wto + (size_t)(mat - 6) * WMAT);
    {
      const int r = tid >> 2, c0 = (tid & 3) << 4;
      if (f32m) {
        const float* wp = reinterpret_cast<const float*>(Wm) + (size_t)(k0 + r) * 768 + n0 + c0;
        #pragma unroll
        for (int j = 0; j < 16; j += 4) {
          float4 v = *reinterpret_cast<const float4*>(wp + j);
          T16[r * 72 + c0 + j + 0] = f2bf(v.x); T16[r * 72 + c0 + j + 1] = f2bf(v.y);
          T16[r * 72 + c0 + j + 2] = f2bf(v.z); T16[r * 72 + c0 + j + 3] = f2bf(v.w);
        }
      } else {
        const u16* wp = reinterpret_cast<const u16*>(Wm) + (size_t)(k0 + r) * 768 + n0 + c0;
        *reinterpret_cast<int4*>(&T16[r * 72 + c0]) = reinterpret_cast<const int4*>(wp)[0];
        *reinterpret_cast<int4*>(&T16[r * 72 + c0 + 8]) = reinterpret_cast<const int4*>(wp)[1];
      }
    }
    __syncthreads();
    {
      const int n = tid >> 2, kc0 = (tid & 3) << 4;
      u16 buf[16];
      #pragma unroll
      for (int j = 0; j < 16; j++) buf[j] = T16[(kc0 + j) * 72 + n];
      u16* op = wbase + (size_t)(n0 + n) * 768 + k0 + kc0;
      *reinterpret_cast<int4*>(op) = *reinterpret_cast<int4*>(buf);
      *reinterpret_cast<int4*>(op + 8) = *reinterpret_cast<int4*>(buf + 8);
    }
  } else if (bid < PKL_BLK + PKG_BLK + WPR_BLK + XPL_BLK + XPG_BLK) {
    // ---- xprep: f32->bf16 (or copy), 8 elems/thread ----
    const int blk = bid - (PKL_BLK + PKG_BLK + WPR_BLK);
    const void* src;
    u16* dst;
    size_t i;
    if (blk < XPL_BLK) {
      src = xlin; dst = xl;
      i = ((size_t)blk * 256 + tid) << 3;
    } else {
      src = xgin; dst = xg;
      i = ((size_t)(blk - XPL_BLK) * 256 + tid) << 3;
    }
    if (f32m) {
      const float* p = reinterpret_cast<const float*>(src) + i;
      float4 a = *reinterpret_cast<const float4*>(p);
      float4 b = *reinterpret_cast<const float4*>(p + 4);
      u16 o[8] = {f2bf(a.x), f2bf(a.y), f2bf(a.z), f2bf(a.w),
                  f2bf(b.x), f2bf(b.y), f2bf(b.z), f2bf(b.w)};
      *reinterpret_cast<int4*>(dst + i) = *reinterpret_cast<int4*>(o);
    } else {
      *reinterpret_cast<int4*>(dst + i) =
          *reinterpret_cast<const int4*>(reinterpret_cast<const u16*>(src) + i);
    }
  } else {
    // ---- M-prep (tiled): block = (side, h, ksp); 128 k-rows per block ----
    const int blk = bid - (PKL_BLK + PKG_BLK + WPR_BLK + XPL_BLK + XPG_BLK);
    const int side = blk / 72;
    const int rem = blk % 72;
    const int h = rem / 6, ksp = rem % 6;
    const int k0 = ksp << 7;
    const void* Wq = side ? W3 : W0;     // wq_g : wq_l
    const void* emb = side ? embg : embl;
    const void* bqv = side ? bqg : bql;
    const void* rbv = side ? rbg : rbl;
    float* Ef = SH;                      // [32][68]
    float* Wf = SH + 32 * 68;            // [64][68]
    float* bqf = SH + 32 * 68 + 64 * 68; // [64]
    float* rbf = bqf + 64;               // [32]
    {
      const int r = tid >> 3, d0 = (tid & 7) << 3;
      #pragma unroll
      for (int j = 0; j < 8; j++)
        Ef[r * 68 + d0 + j] = ldx1(emb, ((size_t)r * HH + h) * DD + d0 + j, f32m);
      if (tid < 64) bqf[tid] = ldx1(bqv, h * 64 + tid, f32m);
      else if (tid < 96) rbf[tid - 64] = ldx1(rbv, (size_t)(tid - 64) * HH + h, f32m);
    }
    __syncthreads();
    if (ksp == 0 && tid < 32) {
      float s = rbf[tid];
      #pragma unroll 16
      for (int d = 0; d < 64; d++) s += bqf[d] * Ef[tid * 68 + d];
      crel[side * 384 + h * 32 + tid] = 0.125f * s;
    }
    const int kr = tid >> 2, rg = tid & 3;
    for (int kt = 0; kt < 2; kt++) {
      const int kb = k0 + (kt << 6);
      {
        const int sr = tid >> 2, d0 = (tid & 3) << 4;
        const size_t base = (size_t)(kb + sr) * 768 + h * 64 + d0;
        if (f32m) {
          const float* wp = reinterpret_cast<const float*>(Wq) + base;
          #pragma unroll
          for (int j = 0; j < 16; j += 4)
            *reinterpret_cast<float4*>(&Wf[sr * 68 + d0 + j]) =
                *reinterpret_cast<const float4*>(wp + j);
        } else {
          const u16* wp = reinterpret_cast<const u16*>(Wq) + base;
          #pragma unroll
          for (int j = 0; j < 16; j += 4) {
            float4 v = ld4bf(wp + j);
            *reinterpret_cast<float4*>(&Wf[sr * 68 + d0 + j]) = v;
          }
        }
      }
      __syncthreads();
      float a[8] = {};
      #pragma unroll
      for (int d = 0; d < 64; d += 4) {
        const float4 wv = *reinterpret_cast<const float4*>(&Wf[kr * 68 + d]);
        #pragma unroll
        for (int j = 0; j < 8; j++) {
          const float4 ev = *reinterpret_cast<const float4*>(&Ef[(rg * 8 + j) * 68 + d]);
          a[j] += wv.x * ev.x + wv.y * ev.y + wv.z * ev.z + wv.w * ev.w;
        }
      }
      #pragma unroll
      for (int j = 0; j < 8; j++)
        wtrel[(size_t)side * MMAT + (size_t)(h * 32 + rg * 8 + j) * 768 + kb + kr] =
            f2bf(0.125f * a[j]);
      __syncthreads();
    }
  }
}

// =========================================================================
// m97-structure GEMM core: 128x128 tile, BK=64, 4 waves (2x2), single-buffer
// LDS staged via global_load_lds(16B) with T2 XOR swizzle.
// =========================================================================
#define GEMM_CORE(A_, Wt_, row0_, ncol0_)                                        \
  __shared__ u16 lds[16384];                                                     \
  const int tid = threadIdx.x;                                                   \
  const int w = tid >> 6, l = tid & 63;                                          \
  const int lm = l & 15, quad = l >> 4;                                          \
  const int wr = w >> 1, wc = w & 1;                                             \
  const int rb = (w << 5) + (l >> 3);                                            \
  const int c8 = (l & 7) ^ (l >> 3);                                             \
  const u16* asrc = A_ + (size_t)(row0_ + rb) * 768 + (c8 << 3);                 \
  const u16* bsrc = Wt_ + (size_t)(ncol0_ + rb) * 768 + (c8 << 3);               \
  u16* adst = lds + (w << 11) + (l << 3);                                        \
  u16* bdst = adst + 8192;                                                       \
  f32x4 acc[4][4];                                                               \
  _Pragma("unroll")                                                              \
  for (int mt = 0; mt < 4; mt++)                                                 \
    _Pragma("unroll")                                                            \
    for (int nt = 0; nt < 4; nt++) acc[mt][nt] = (f32x4){0.f, 0.f, 0.f, 0.f};    \
  const char* abase = reinterpret_cast<const char*>(lds);                        \
  const char* bbase = abase + 16384;                                             \
  const int xorv = (lm & 7) << 4;                                                \
  for (int k0 = 0; k0 < 768; k0 += 64) {                                         \
    __syncthreads();                                                             \
    _Pragma("unroll")                                                            \
    for (int i = 0; i < 4; i++) gload16(asrc + k0 + i * 6144, adst + (i << 9));  \
    _Pragma("unroll")                                                            \
    for (int i = 0; i < 4; i++) gload16(bsrc + k0 + i * 6144, bdst + (i << 9));  \
    __syncthreads();                                                             \
    _Pragma("unroll")                                                            \
    for (int kk = 0; kk < 2; kk++) {                                             \
      bf16x8 af[4], bfr[4];                                                      \
      _Pragma("unroll")                                                          \
      for (int mt = 0; mt < 4; mt++)                                             \
        af[mt] = *reinterpret_cast<const bf16x8*>(                               \
            abase + ((wr << 6) + (mt << 4) + lm) * 128 +                         \
            (((kk << 6) + (quad << 4)) ^ xorv));                                 \
      _Pragma("unroll")                                                          \
      for (int nt = 0; nt < 4; nt++)                                             \
        bfr[nt] = *reinterpret_cast<const bf16x8*>(                              \
            bbase + ((wc << 6) + (nt << 4) + lm) * 128 +                         \
            (((kk << 6) + (quad << 4)) ^ xorv));                                 \
      _Pragma("unroll")                                                          \
      for (int mt = 0; mt < 4; mt++)                                             \
        _Pragma("unroll")                                                        \
        for (int nt = 0; nt < 4; nt++)                                           \
          acc[mt][nt] = __builtin_amdgcn_mfma_f32_16x16x32_bf16(                 \
              af[mt], bfr[nt], acc[mt][nt], 0, 0, 0);                            \
    }                                                                            \
  }

// ---------- fused QKV+rel GEMM, long U glob in one launch (1428 blocks) ----------
// lx 0..17 -> Q/K/V columns (Wt); lx 18..20 -> rel columns (Mt fold).
__global__ __launch_bounds__(256)
void gemm_qkv(const u16* __restrict__ Al, const u16* __restrict__ Ag,
              const u16* __restrict__ Wtq, const u16* __restrict__ Wtr,
              const float* __restrict__ crel,
              const void* __restrict__ bql, const void* __restrict__ bkl,
              const void* __restrict__ bvl,
              const void* __restrict__ bqg, const void* __restrict__ bkg,
              const void* __restrict__ bvg,
              u16* __restrict__ lq, u16* __restrict__ lk, u16* __restrict__ lv,
              u16* __restrict__ gq, u16* __restrict__ gk, u16* __restrict__ gv,
              u16* __restrict__ rell, u16* __restrict__ relg,
              const int* __restrict__ flagp) {
  const bool f32m = (*flagp != 0);
  const int fid = blockIdx.x;
  int lx, ly;
  bool isL;
  if (fid < 1344) {          // long, XCD-swizzled: XCD x owns ly in [8x,8x+8)
    isL = true;
    const int x = fid & 7, rr = fid >> 3;
    ly = (x << 3) | (rr & 7);
    lx = rr >> 3;
  } else {                   // glob
    isL = false;
    const int g = fid - 1344;
    lx = g % 21; ly = g / 21;
  }
  const u16* A = isL ? Al : Ag;
  const u16* Wsel;
  int ncolw;
  if (lx < 18) { Wsel = isL ? Wtq : (Wtq + (size_t)3 * WMAT); ncolw = lx << 7; }
  else         { Wsel = Wtr + (isL ? 0 : (size_t)MMAT);       ncolw = (lx - 18) << 7; }
  const int row0 = ly << 7;
  GEMM_CORE(A, Wsel, row0, ncolw)

  if (lx < 18) {
    const int which = lx / 6;
    const void* bias = (which == 0) ? (isL ? bql : bqg)
                     : (which == 1) ? (isL ? bkl : bkg) : (isL ? bvl : bvg);
    u16* Cv = (which == 0) ? (isL ? lq : gq)
            : (which == 1) ? (isL ? lk : gk) : (isL ? lv : gv);
    const float sc = (which == 0) ? 0.125f : 1.0f;   // fold softmax scale into Q
    const int colw = (lx % 6) << 7;
    #pragma unroll
    for (int nt = 0; nt < 4; nt++) {
      const int gcol = colw + (wc << 6) + (nt << 4) + lm;
      const float bv = ldx1(bias, gcol, f32m);
      #pragma unroll
      for (int mt = 0; mt < 4; mt++)
        #pragma unroll
        for (int r = 0; r < 4; r++) {
          const int grow = row0 + (wr << 6) + (mt << 4) + (quad << 2) + r;
          Cv[(size_t)grow * 768 + gcol] = f2bf((acc[mt][nt][r] + bv) * sc);
        }
    }
  } else {
    const float* cr = crel + (isL ? 0 : 384);
    u16* ro = isL ? rell : relg;
    #pragma unroll
    for (int nt = 0; nt < 4; nt++) {
      const int gcol = ncolw + (wc << 6) + (nt << 4) + lm;
      const float cv = cr[gcol];
      #pragma unroll
      for (int mt = 0; mt < 4; mt++)
        #pragma unroll
        for (int r = 0; r < 4; r++) {
          const int grow = row0 + (wr << 6) + (mt << 4) + (quad << 2) + r;
          ro[(size_t)grow * 384 + gcol] = f2bf(acc[mt][nt][r] + cv);
        }
    }
  }
}

// ---------- output-projection GEMM, long U glob (408 blocks) ----------
__global__ __launch_bounds__(256)
void gemm_out(const u16* __restrict__ Alc, const u16* __restrict__ Agc,
              const u16* __restrict__ Wto,
              const void* __restrict__ bol, const void* __restrict__ bog,
              void* __restrict__ Cv, const int* __restrict__ flagp) {
  const bool f32m = (*flagp != 0);
  const int fid = blockIdx.x;
  int lx, ly;
  const u16 *A, *Wt;
  const void* bias;
  size_t c_off;
  if (fid < 384) {           // long, XCD-swizzled
    const int x = fid & 7, r = fid >> 3;
    ly = (x << 3) | (r & 7);
    lx = r >> 3;
    A = Alc; Wt = Wto; bias = bol; c_off = 0;
  } else {
    const int g = fid - 384;
    lx = g % 6; ly = g / 6;
    A = Agc; Wt = Wto + WMAT; bias = bog; c_off = (size_t)BB * LL * 768;
  }
  const int row0 = ly << 7;
  const int ncol0 = lx << 7;
  GEMM_CORE(A, Wt, row0, ncol0)

  #pragma unroll
  for (int nt = 0; nt < 4; nt++) {
    const int gcol = ncol0 + (wc << 6) + (nt << 4) + lm;
    const float bv = ldx1(bias, gcol, f32m);
    #pragma unroll
    for (int mt = 0; mt < 4; mt++)
      #pragma unroll
      for (int r = 0; r < 4; r++) {
        const int grow = row0 + (wr << 6) + (mt << 4) + (quad << 2) + r;
        const float v = acc[mt][nt][r] + bv;
        if (f32m)
          reinterpret_cast<float*>(Cv)[c_off + (size_t)grow * 768 + gcol] = v;
        else
          reinterpret_cast<u16*>(Cv)[c_off + (size_t)grow * 768 + gcol] = f2bf(v);
      }
  }
}

// ---------- merged attention: lattn (blocks 0..767) U gattn (768..1583) ----------
// Both bodies verbatim from the passing round-9/10 kernels; shared LDS shapes
// identical. sigma(k) = (k&15)*4 + (k>>4) P/V permutation; cvt_pk P store.
__global__ __launch_bounds__(512)
void attn(const u16* __restrict__ lq, const u16* __restrict__ lk, const u16* __restrict__ lv,
          const u16* __restrict__ gq, const u16* __restrict__ gk, const u16* __restrict__ gv,
          const u32* __restrict__ pkl, const u32* __restrict__ pkg,
          const u16* __restrict__ rell, const u16* __restrict__ relg,
          u16* __restrict__ lctx, float* __restrict__ po, float* __restrict__ pl) {
  __shared__ u16 Kt[64][72];
  __shared__ u16 Vt[64][74];
  __shared__ u16 Pt[128][76];
  __shared__ u16 Rw[128][36];

  const int tid = threadIdx.x;
  const int lane = tid & 63, wv = tid >> 6;
  const int ln = lane & 15, quad = lane >> 4;
  const int skey = tid >> 3, sdg = (tid & 7) << 3;
  const int scol = ((skey & 15) << 2) | (skey >> 4);      // sigma(skey)

  if (blockIdx.x < 768) {
    // ================= lattn =================
    const int fid = blockIdx.x;
    const int hg = fid >> 3;                       // 0..95
    const int h = hg % 12;
    const int fl = (fid & 7) + ((hg / 12) << 3);   // 0..63 = b*32+n
    const int n = fl & 31, b = fl >> 5;
    const int tbase = n << 7;

    {
      const int qr = (wv << 4) + (lane >> 2);
      const int seg = (lane & 3) << 3;
      *reinterpret_cast<int4*>(&Rw[qr][seg]) = *reinterpret_cast<const int4*>(
          rell + ((size_t)(b * LL + tbase + qr)) * 384 + h * 32 + seg);
    }

    bf16x8 aq[2];
    {
      const int t = tbase + (wv << 4) + ln;
      const u16* qp = lq + (((size_t)b * LL + t) * HH + h) * DD + (quad << 3);
      aq[0] = *reinterpret_cast<const bf16x8*>(qp);
      aq[1] = *reinterpret_cast<const bf16x8*>(qp + 32);
    }

    const u32* pk32 = pkl + (size_t)(b * 32 + n) * 20480;   // 10*128*16 u32

    f32x4 Oacc[4];
    #pragma unroll
    for (int dt = 0; dt < 4; dt++) Oacc[dt] = (f32x4){0.f, 0.f, 0.f, 0.f};
    float lpart[4] = {};

    for (int tile = 0; tile < 10; tile++) {
      const int c0 = tile << 6;
      const bool isg = (tile >= 6);

      float badd[16];
      #pragma unroll
      for (int r = 0; r < 4; r++) {
        const int qrow = (wv << 4) + (quad << 2) + r;
        const u32 pw = pk32[(((tile << 7) + qrow) << 4) + ln];
        #pragma unroll
        for (int kt = 0; kt < 4; kt++) {
          const u32 pb = (pw >> (kt << 3)) & 0xFFu;
          const float rv = bf2f(Rw[qrow][pb & 31]);
          badd[(kt << 2) + r] = (pb & 0x80u) ? (rv - 10000.f) : rv;
        }
      }

      __syncthreads();
      {
        int4 kraw = {0, 0, 0, 0}, vraw = {0, 0, 0, 0};
        if (isg) {
          const size_t base = (((size_t)b * GG + (c0 - 384) + skey) * HH + h) * DD + sdg;
          kraw = *reinterpret_cast<const int4*>(gk + base);
          vraw = *reinterpret_cast<const int4*>(gv + base);
        } else {
          const int jabs = ((n - 1) << 7) + c0 + skey;
          if (jabs >= 0 && jabs < LL) {
            const size_t base = (((size_t)b * LL + jabs) * HH + h) * DD + sdg;
            kraw = *reinterpret_cast<const int4*>(lk + base);
            vraw = *reinterpret_cast<const int4*>(lv + base);
          }
        }
        *reinterpret_cast<int4*>(&Kt[skey][sdg]) = kraw;
        u16 vb[8];
        *reinterpret_cast<int4*>(vb) = vraw;
        #pragma unroll
        for (int j = 0; j < 8; j++) Vt[sdg + j][scol] = vb[j];
      }
      __syncthreads();

      f32x4 Sacc[4];
      #pragma unroll
      for (int kt = 0; kt < 4; kt++) Sacc[kt] = (f32x4){0.f, 0.f, 0.f, 0.f};
      __builtin_amdgcn_s_setprio(1);
      #pragma unroll
      for (int kk = 0; kk < 2; kk++) {
        bf16x8 bk[4];
        #pragma unroll
        for (int kt = 0; kt < 4; kt++)
          bk[kt] = *reinterpret_cast<const bf16x8*>(&Kt[(kt << 4) + ln][(kk << 5) + (quad << 3)]);
        #pragma unroll
        for (int kt = 0; kt < 4; kt++)
          Sacc[kt] = __builtin_amdgcn_mfma_f32_16x16x32_bf16(aq[kk], bk[kt], Sacc[kt], 0, 0, 0);
      }
      __builtin_amdgcn_s_setprio(0);

      #pragma unroll
      for (int r = 0; r < 4; r++) {
        const int ql = (wv << 4) + (quad << 2) + r;
        const float p0 = __expf(Sacc[0][r] + badd[0 + r]);
        const float p1 = __expf(Sacc[1][r] + badd[4 + r]);
        const float p2 = __expf(Sacc[2][r] + badd[8 + r]);
        const float p3 = __expf(Sacc[3][r] + badd[12 + r]);
        u32 w0, w1;
        asm("v_cvt_pk_bf16_f32 %0, %1, %2" : "=v"(w0) : "v"(p0), "v"(p1));
        asm("v_cvt_pk_bf16_f32 %0, %1, %2" : "=v"(w1) : "v"(p2), "v"(p3));
        uint2 wp; wp.x = w0; wp.y = w1;
        *reinterpret_cast<uint2*>(&Pt[ql][ln << 2]) = wp;
        lpart[r] += (p0 + p1) + (p2 + p3);
      }

      __builtin_amdgcn_s_setprio(1);
      #pragma unroll
      for (int kk = 0; kk < 2; kk++) {
        bf16x8 ap = *reinterpret_cast<const bf16x8*>(&Pt[(wv << 4) + ln][(kk << 5) + (quad << 3)]);
        #pragma unroll
        for (int dt = 0; dt < 4; dt++) {
          bf16x8 bv = *reinterpret_cast<const bf16x8*>(&Vt[(dt << 4) + ln][(kk << 5) + (quad << 3)]);
          Oacc[dt] = __builtin_amdgcn_mfma_f32_16x16x32_bf16(ap, bv, Oacc[dt], 0, 0, 0);
        }
      }
      __builtin_amdgcn_s_setprio(0);
    }

    #pragma unroll
    for (int r = 0; r < 4; r++) {
      float v = lpart[r];
      v += __shfl_xor(v, 1); v += __shfl_xor(v, 2);
      v += __shfl_xor(v, 4); v += __shfl_xor(v, 8);
      const float inv = 1.0f / v;
      const int t = tbase + (wv << 4) + (quad << 2) + r;
      const size_t base = (((size_t)b * LL + t) * HH + h) * DD;
      #pragma unroll
      for (int dt = 0; dt < 4; dt++)
        lctx[base + (dt << 4) + ln] = f2bf(Oacc[dt][r] * inv);
    }
  } else {
    // ================= gattn =================
    const int fid = blockIdx.x - 768;
    const int x = fid & 7;
    const int slot = fid >> 3;            // 0..101
    const int qtp = slot & 1;
    const int g = ((slot >> 1) << 3) | x; // 0..407
    const int h = g % 12;
    const int cb = g / 12;                // 0..33
    const int chunk = cb % 17;
    const int b = cb / 17;
    const int qbase = qtp << 7;
    const int kbase = chunk << 8;
    const bool isgg = (chunk == 0);

    {
      const int qr = (wv << 4) + (lane >> 2);
      const int seg = (lane & 3) << 3;
      *reinterpret_cast<int4*>(&Rw[qr][seg]) = *reinterpret_cast<const int4*>(
          relg + ((size_t)(b * GG + qbase + qr)) * 384 + h * 32 + seg);
    }

    bf16x8 aq[2];
    {
      const int qa = qbase + (wv << 4) + ln;
      const u16* qp = gq + (((size_t)b * GG + qa) * HH + h) * DD + (quad << 3);
      aq[0] = *reinterpret_cast<const bf16x8*>(qp);
      aq[1] = *reinterpret_cast<const bf16x8*>(qp + 32);
    }

    const u32* pk32 = pkg + (size_t)((b << 1) + qtp) * 139264;  // 68*128*16 u32

    f32x4 Oacc[4];
    #pragma unroll
    for (int dt = 0; dt < 4; dt++) Oacc[dt] = (f32x4){0.f, 0.f, 0.f, 0.f};
    float lpart[4] = {};

    for (int tile = 0; tile < 4; tile++) {
      const int tl = (chunk << 2) + tile;

      float badd[16];
      #pragma unroll
      for (int r = 0; r < 4; r++) {
        const int qrow = (wv << 4) + (quad << 2) + r;
        const u32 pw = pk32[(((tl << 7) + qrow) << 4) + ln];
        #pragma unroll
        for (int kt = 0; kt < 4; kt++) {
          const u32 pb = (pw >> (kt << 3)) & 0xFFu;
          const float rv = bf2f(Rw[qrow][pb & 31]);
          badd[(kt << 2) + r] = (pb & 0x80u) ? (rv - 10000.f) : rv;
        }
      }

      __syncthreads();
      {
        const int kc = kbase + (tile << 6) + skey;
        int4 kraw, vraw;
        if (isgg) {
          const size_t base = (((size_t)b * GG + kc) * HH + h) * DD + sdg;
          kraw = *reinterpret_cast<const int4*>(gk + base);
          vraw = *reinterpret_cast<const int4*>(gv + base);
        } else {
          const size_t base = (((size_t)b * LL + (kc - 256)) * HH + h) * DD + sdg;
          kraw = *reinterpret_cast<const int4*>(lk + base);
          vraw = *reinterpret_cast<const int4*>(lv + base);
        }
        *reinterpret_cast<int4*>(&Kt[skey][sdg]) = kraw;
        u16 vb[8];
        *reinterpret_cast<int4*>(vb) = vraw;
        #pragma unroll
        for (int j = 0; j < 8; j++) Vt[sdg + j][scol] = vb[j];
      }
      __syncthreads();

      f32x4 Sacc[4];
      #pragma unroll
      for (int kt = 0; kt < 4; kt++) Sacc[kt] = (f32x4){0.f, 0.f, 0.f, 0.f};
      __builtin_amdgcn_s_setprio(1);
      #pragma unroll
      for (int kk = 0; kk < 2; kk++) {
        bf16x8 bk[4];
        #pragma unroll
        for (int kt = 0; kt < 4; kt++)
          bk[kt] = *reinterpret_cast<const bf16x8*>(&Kt[(kt << 4) + ln][(kk << 5) + (quad << 3)]);
        #pragma unroll
        for (int kt = 0; kt < 4; kt++)
          Sacc[kt] = __builtin_amdgcn_mfma_f32_16x16x32_bf16(aq[kk], bk[kt], Sacc[kt], 0, 0, 0);
      }
      __builtin_amdgcn_s_setprio(0);

      #pragma unroll
      for (int r = 0; r < 4; r++) {
        const int ql = (wv << 4) + (quad << 2) + r;
        const float p0 = __expf(Sacc[0][r] + badd[0 + r]);
        const float p1 = __expf(Sacc[1][r] + badd[4 + r]);
        const float p2 = __expf(Sacc[2][r] + badd[8 + r]);
        const float p3 = __expf(Sacc[3][r] + badd[12 + r]);
        u32 w0, w1;
        asm("v_cvt_pk_bf16_f32 %0, %1, %2" : "=v"(w0) : "v"(p0), "v"(p1));
        asm("v_cvt_pk_bf16_f32 %0, %1, %2" : "=v"(w1) : "v"(p2), "v"(p3));
        uint2 wp; wp.x = w0; wp.y = w1;
        *reinterpret_cast<uint2*>(&Pt[ql][ln << 2]) = wp;
        lpart[r] += (p0 + p1) + (p2 + p3);
      }

      __builtin_amdgcn_s_setprio(1);
      #pragma unroll
      for (int kk = 0; kk < 2; kk++) {
        bf16x8 ap = *reinterpret_cast<const bf16x8*>(&Pt[(wv << 4) + ln][(kk << 5) + (quad << 3)]);
        #pragma unroll
        for (int dt = 0; dt < 4; dt++) {
          bf16x8 bv = *reinterpret_cast<const bf16x8*>(&Vt[(dt << 4) + ln][(kk << 5) + (quad << 3)]);
          Oacc[dt] = __builtin_amdgcn_mfma_f32_16x16x32_bf16(ap, bv, Oacc[dt], 0, 0, 0);
        }
      }
      __builtin_amdgcn_s_setprio(0);
    }

    #pragma unroll
    for (int r = 0; r < 4; r++) {
      float v = lpart[r];
      v += __shfl_xor(v, 1); v += __shfl_xor(v, 2);
      v += __shfl_xor(v, 4); v += __shfl_xor(v, 8);
      const int qa = qbase + (wv << 4) + (quad << 2) + r;
      if (ln == 0)
        pl[(((size_t)chunk * BB + b) * HH + h) * GG + qa] = v;
      const size_t base = ((((size_t)chunk * BB + b) * HH + h) * GG + qa) * DD;
      #pragma unroll
      for (int dt = 0; dt < 4; dt++)
        po[base + (dt << 4) + ln] = Oacc[dt][r];
    }
  }
}

// ---------- combine global-attention partials (17 chunks) ----------
__global__ __launch_bounds__(256)
void gcombine(const float* __restrict__ po, const float* __restrict__ pl,
              u16* __restrict__ gctx) {
  const int flat = blockIdx.x * 256 + threadIdx.x;
  const int d = flat & 63;
  const int rest = flat >> 6;
  const int h = rest % HH;
  const int bq = rest / HH;
  const int b = bq >> 8, qg = bq & 255;
  float so = 0.f, sl = 0.f;
  #pragma unroll
  for (int c = 0; c < NCHUNK; c++) {
    so += po[((((size_t)c * BB + b) * HH + h) * GG + qg) * DD + d];
    sl += pl[(((size_t)c * BB + b) * HH + h) * GG + qg];
  }
  gctx[flat] = f2bf(so / sl);
}

// ---------- host launch ----------
extern "C" void kernel_launch(void* const* d_in, const int* in_sizes, int n_in,
                              void* d_out, int out_size, void* d_ws, size_t ws_size,
                              hipStream_t stream) {
  (void)in_sizes; (void)n_in; (void)out_size; (void)ws_size;
  const void* x_long = d_in[0];
  const void* x_glob = d_in[1];
  const int* m_l2l = (const int*)d_in[2];
  const int* m_g2g = (const int*)d_in[3];
  const int* m_l2g = (const int*)d_in[4];
  const int* m_g2l = (const int*)d_in[5];
  const int* i_l2l = (const int*)d_in[6];
  const int* i_g2g = (const int*)d_in[7];
  const int* i_l2g = (const int*)d_in[8];
  const int* i_g2l = (const int*)d_in[9];
  const void* wq_l = d_in[10]; const void* bq_l = d_in[11];
  const void* wk_l = d_in[12]; const void* bk_l = d_in[13];
  const void* wv_l = d_in[14]; const void* bv_l = d_in[15];
  const void* wq_g = d_in[16]; const void* bq_g = d_in[17];
  const void* wk_g = d_in[18]; const void* bk_g = d_in[19];
  const void* wv_g = d_in[20]; const void* bv_g = d_in[21];
  const void* rel_emb_l = d_in[22]; const void* rel_bias_l = d_in[23];
  const void* rel_emb_g = d_in[24]; const void* rel_bias_g = d_in[25];
  const void* wo_l = d_in[26]; const void* bo_l = d_in[27];
  const void* wo_g = d_in[28]; const void* bo_g = d_in[29];

  constexpr size_t NLQ = (size_t)BB * LL * HH * DD;
  constexpr size_t NG  = (size_t)BB * GG * HH * DD;
  constexpr size_t NRL = (size_t)BB * LL * HH * VV;
  constexpr size_t NRG = (size_t)BB * GG * HH * VV;
  u16* lqw  = reinterpret_cast<u16*>(d_ws);
  u16* lkw  = lqw + NLQ;
  u16* lvw  = lkw + NLQ;
  u16* gqw  = lvw + NLQ;
  u16* gkw  = gqw + NG;
  u16* gvw  = gkw + NG;
  u16* rell = gvw + NG;
  u16* relg = rell + NRL;
  u16* lctx = relg + NRG;
  u16* gctx = lctx + NLQ;
  int* flag = reinterpret_cast<int*>(gctx + NG);
  float* po = reinterpret_cast<float*>(flag + 16);          // [17][B][H][G][D]
  float* pl = po + (size_t)NCHUNK * BB * HH * GG * DD;      // [17][B][H][G]
  // Overlays (same-stream liveness):
  //  pk_l   -> po base      (dead once attn's lattn-half finishes; gattn-half
  //                          writes po in the SAME launch -- but pk_l is only
  //                          read by lattn blocks and po only written by gattn
  //                          blocks at the same addresses... NOT safe to overlap
  //                          within one launch. pk_l therefore moved past pk_g.
  u16* wt_qkv = reinterpret_cast<u16*>(po) + 2621440;       // 6 mats x WMAT (dead after gemm_qkv)
  u16* xl_bf = lctx;
  u16* xg_bf = gctx;
  u8* pk_g = reinterpret_cast<u8*>(pl + (size_t)NCHUNK * BB * HH * GG);  // [B*2][68][128][64]
  u8* pk_l = pk_g + (size_t)BB * GG * GKEY;                 // [B*32][10][128][64] = 5.24 MB
  u16* wt_o = reinterpret_cast<u16*>(pk_l + (size_t)BB * LL * LKEY);     // 2 mats x WMAT
  u16* wt_rel = wt_o + (size_t)2 * WMAT;                    // 2 x [384][768] bf16
  float* c_rel = reinterpret_cast<float*>(wt_rel + (size_t)2 * MMAT);    // [768] f32

  dim3 t256(256);
  detect_dtype<<<1, t256, 0, stream>>>(x_long, flag);
  prep<<<dim3(PKL_BLK + PKG_BLK + WPR_BLK + XPL_BLK + XPG_BLK + MPR_BLK), t256, 0, stream>>>(
      m_l2l, m_l2g, i_l2l, i_l2g, m_g2g, m_g2l, i_g2g, i_g2l, pk_l, pk_g,
      wq_l, wk_l, wv_l, wq_g, wk_g, wv_g, wo_l, wo_g, wt_qkv, wt_o,
      x_long, x_glob, xl_bf, xg_bf,
      rel_emb_l, rel_bias_l, rel_emb_g, rel_bias_g, bq_l, bq_g,
      wt_rel, c_rel, flag);
  gemm_qkv<<<dim3(1428), t256, 0, stream>>>(
      xl_bf, xg_bf, wt_qkv, wt_rel, c_rel,
      bq_l, bk_l, bv_l, bq_g, bk_g, bv_g,
      lqw, lkw, lvw, gqw, gkw, gvw, rell, relg, flag);
  attn<<<dim3(1584), dim3(512), 0, stream>>>(
      lqw, lkw, lvw, gqw, gkw, gvw,
      reinterpret_cast<const u32*>(pk_l), reinterpret_cast<const u32*>(pk_g),
      rell, relg, lctx, po, pl);
  gcombine<<<dim3(1536), t256, 0, stream>>>(po, pl, gctx);
  gemm_out<<<dim3(408), t256, 0, stream>>>(lctx, gctx, wt_o, bo_l, bo_g, d_out, flag);
}